// Round 7
// baseline (609.331 us; speedup 1.0000x reference)
//
#include <hip/hip_runtime.h>
#include <hip/hip_bf16.h>

#define BEPS 1e-5f
#define FC1_KS 98
#define FC1_KC 256
#define C1NB 2017

typedef __attribute__((ext_vector_type(8))) short short8v;
typedef __attribute__((ext_vector_type(4))) float f32x4;
typedef unsigned short ushort_t;

__device__ __forceinline__ float bf2f(ushort_t u) {
    unsigned int x = ((unsigned int)u) << 16;
    return __builtin_bit_cast(float, x);
}

// ---------------- conv1: direct fp32, bf16 out (no stats) -------------------
__global__ __launch_bounds__(256) void conv1_direct(
    const float* __restrict__ in, const float* __restrict__ w,
    const float* __restrict__ bias, __hip_bfloat16* __restrict__ out) {
    __shared__ float ws[864];
    __shared__ float bs[32];
    const int tid = threadIdx.x;
    for (int i = tid; i < 864; i += 256) ws[i] = w[i];
    if (tid < 32) bs[tid] = bias[tid];
    __syncthreads();

    const int TOT = 32 * 16129;
    int p = blockIdx.x * 256 + tid;
    if (p >= TOT) return;
    int b = p / 16129, pp = p - b * 16129;
    int i = pp / 127, j = pp - i * 127;
    const float* ib = in + ((long long)b * 3) * 65536 + (2 * i) * 256 + 2 * j;
    float patch[27];
#pragma unroll
    for (int ci = 0; ci < 3; ++ci)
#pragma unroll
        for (int di = 0; di < 3; ++di) {
            const float* rp = ib + ci * 65536 + di * 256;
            float2 v01 = *(const float2*)rp;
            patch[ci * 9 + di * 3 + 0] = v01.x;
            patch[ci * 9 + di * 3 + 1] = v01.y;
            patch[ci * 9 + di * 3 + 2] = rp[2];
        }

#pragma unroll
    for (int co = 0; co < 32; co += 4) {
        float a0 = bs[co], a1 = bs[co + 1], a2 = bs[co + 2], a3 = bs[co + 3];
#pragma unroll
        for (int t = 0; t < 27; ++t) {
            float pv = patch[t];
            a0 = fmaf(pv, ws[(co + 0) * 27 + t], a0);
            a1 = fmaf(pv, ws[(co + 1) * 27 + t], a1);
            a2 = fmaf(pv, ws[(co + 2) * 27 + t], a2);
            a3 = fmaf(pv, ws[(co + 3) * 27 + t], a3);
        }
        out[((long long)b * 32 + co + 0) * 16129 + pp] = __float2bfloat16(fmaxf(a0, 0.f));
        out[((long long)b * 32 + co + 1) * 16129 + pp] = __float2bfloat16(fmaxf(a1, 0.f));
        out[((long long)b * 32 + co + 2) * 16129 + pp] = __float2bfloat16(fmaxf(a2, 0.f));
        out[((long long)b * 32 + co + 3) * 16129 + pp] = __float2bfloat16(fmaxf(a3, 0.f));
    }
}

// ---------------- convs 2-5: bf16 MFMA implicit GEMM ------------------------
__global__ __launch_bounds__(256) void conv_mfma(
    const __hip_bfloat16* __restrict__ in, const ushort_t* __restrict__ wf,
    const float* __restrict__ effb, __hip_bfloat16* __restrict__ out,
    float* __restrict__ pacc,
    int B, int Ci, int Hi, int Wi, int Co, int Ho, int Wo, int K, int kcount) {
    const int HoWo = Ho * Wo;
    const int N = B * HoWo;
    const int HiWi = Hi * Wi;
    __shared__ __align__(16) ushort_t As[64 * 40];
    __shared__ __align__(16) ushort_t Bs[64 * 40];
    __shared__ int koff[1152];
    const int tid = threadIdx.x;
    const int m0 = blockIdx.y * 64;
    const int n0 = blockIdx.x * 64;
    const int kbeg = blockIdx.z * kcount;

    for (int k = tid; k < kcount; k += 256) {
        int kg = kbeg + k;
        int ci = kg / 9, r = kg - ci * 9;
        int dy = r / 3, dx = r - dy * 3;
        koff[k] = ci * HiWi + dy * Wi + dx;
    }

    const int srow = tid >> 2;
    const int skq = (tid & 3) * 8;
    const int n = n0 + srow;
    const bool nv = (n < N);
    const int nn = nv ? n : 0;
    const int pb = nn / HoWo, pp = nn - pb * HoWo;
    const int pi = pp / Wo, pj = pp - pi * Wo;
    const long long binbase = (long long)pb * Ci * HiWi + (2 * pi) * Wi + 2 * pj;
    const ushort_t* inq = (const ushort_t*)in;
    const ushort_t* wrow = wf + (long long)(m0 + srow) * K + kbeg + skq;

    const int wid = tid >> 6;
    const int lane = tid & 63;
    const int wr = wid >> 1, wc = wid & 1;
    const int lm = lane & 15, lk = lane >> 4;

    __syncthreads();  // koff ready

    f32x4 acc[2][2] = {};
    for (int k0 = 0; k0 < kcount; k0 += 32) {
        *(short8v*)&As[srow * 40 + skq] = *(const short8v*)(wrow + k0);
        short8v bvv;
#pragma unroll
        for (int j = 0; j < 8; ++j) {
            ushort_t v = nv ? inq[binbase + koff[k0 + skq + j]] : (ushort_t)0;
            bvv[j] = (short)v;
        }
        *(short8v*)&Bs[srow * 40 + skq] = bvv;
        __syncthreads();
        short8v a0 = *(const short8v*)&As[(wr * 32 + lm) * 40 + lk * 8];
        short8v a1 = *(const short8v*)&As[(wr * 32 + 16 + lm) * 40 + lk * 8];
        short8v b0 = *(const short8v*)&Bs[(wc * 32 + lm) * 40 + lk * 8];
        short8v b1 = *(const short8v*)&Bs[(wc * 32 + 16 + lm) * 40 + lk * 8];
        acc[0][0] = __builtin_amdgcn_mfma_f32_16x16x32_bf16(a0, b0, acc[0][0], 0, 0, 0);
        acc[0][1] = __builtin_amdgcn_mfma_f32_16x16x32_bf16(a0, b1, acc[0][1], 0, 0, 0);
        acc[1][0] = __builtin_amdgcn_mfma_f32_16x16x32_bf16(a1, b0, acc[1][0], 0, 0, 0);
        acc[1][1] = __builtin_amdgcn_mfma_f32_16x16x32_bf16(a1, b1, acc[1][1], 0, 0, 0);
        __syncthreads();
    }
    if (pacc) {
        float* pbuf = pacc + (long long)blockIdx.z * Co * N;
#pragma unroll
        for (int nc = 0; nc < 2; ++nc) {
            int np = n0 + wc * 32 + nc * 16 + lm;
            if (np >= N) continue;
#pragma unroll
            for (int mr = 0; mr < 2; ++mr) {
                int cobase = m0 + wr * 32 + mr * 16 + lk * 4;
#pragma unroll
                for (int r = 0; r < 4; ++r)
                    pbuf[(long long)(cobase + r) * N + np] = acc[mr][nc][r];
            }
        }
    } else {
#pragma unroll
        for (int nc = 0; nc < 2; ++nc) {
            int np = n0 + wc * 32 + nc * 16 + lm;
            if (np >= N) continue;
            int ob = np / HoWo, op = np - ob * HoWo;
#pragma unroll
            for (int mr = 0; mr < 2; ++mr) {
                int cobase = m0 + wr * 32 + mr * 16 + lk * 4;
#pragma unroll
                for (int r = 0; r < 4; ++r) {
                    int co = cobase + r;
                    float v = fmaxf(acc[mr][nc][r] + effb[co], 0.f);
                    out[((long long)ob * Co + co) * HoWo + op] = __float2bfloat16(v);
                }
            }
        }
    }
}

// reduce conv5 K-split partials + bias + relu -> bf16 NCHW
__global__ void conv5_reduce(const float* __restrict__ pacc, const float* __restrict__ effb,
                             __hip_bfloat16* __restrict__ out) {
    int idx = blockIdx.x * 256 + threadIdx.x;
    if (idx >= 512 * 1568) return;
    int co = idx / 1568, n = idx - co * 1568;
    const long long st = (long long)512 * 1568;
    float s = pacc[(long long)co * 1568 + n] + pacc[st + (long long)co * 1568 + n] +
              pacc[2 * st + (long long)co * 1568 + n] + effb[co];
    s = fmaxf(s, 0.f);
    int b = n / 49, p = n - b * 49;
    out[((long long)b * 512 + co) * 49 + p] = __float2bfloat16(s);
}

// ---------------- BN stats (bf16 input), vectorized short8 ------------------
__global__ __launch_bounds__(256) void stats_partial_v(
    const ushort_t* __restrict__ y, float* __restrict__ part,
    int B, int C, int HW, int S) {
    const int c = blockIdx.x;
    const int s = blockIdx.y;
    const int tid = threadIdx.x;
    float sum = 0.f, sq = 0.f;
    for (int b = 0; b < B; ++b) {
        long long base = ((long long)b * C + c) * HW;
        long long end = base + HW;
        long long a0 = (base + 7) & ~7LL;
        long long a1 = end & ~7LL;
        if (s == 0) {
            int hn = (int)(a0 - base);
            if (tid < hn) {
                float v = bf2f(y[base + tid]);
                sum += v; sq = fmaf(v, v, sq);
            }
            int tn = (int)(end - a1);
            if (tid >= 8 && tid < 8 + tn) {
                float v = bf2f(y[a1 + tid - 8]);
                sum += v; sq = fmaf(v, v, sq);
            }
        }
        int nv8 = (int)((a1 - a0) >> 3);
        for (int ch = s * 256 + tid; ch < nv8; ch += S * 256) {
            short8v v8 = *(const short8v*)(y + a0 + (long long)ch * 8);
#pragma unroll
            for (int j = 0; j < 8; ++j) {
                float v = bf2f((ushort_t)v8[j]);
                sum += v; sq = fmaf(v, v, sq);
            }
        }
    }
    __shared__ float ls[256], lq[256];
    ls[tid] = sum; lq[tid] = sq;
    __syncthreads();
    for (int o = 128; o > 0; o >>= 1) {
        if (tid < o) { ls[tid] += ls[tid + o]; lq[tid] += lq[tid + o]; }
        __syncthreads();
    }
    if (tid == 0) {
        part[(c * S + s) * 2 + 0] = ls[0];
        part[(c * S + s) * 2 + 1] = lq[0];
    }
}

__global__ void stats_final(const float* __restrict__ part, const float* __restrict__ g,
                            const float* __restrict__ be, float* __restrict__ scale,
                            float* __restrict__ shift, int C, int S, float invN) {
    int c = blockIdx.x * blockDim.x + threadIdx.x;
    if (c >= C) return;
    float s = 0.f, q = 0.f;
    for (int i = 0; i < S; ++i) {
        s += part[(c * S + i) * 2 + 0];
        q += part[(c * S + i) * 2 + 1];
    }
    float m = s * invN;
    float v = q * invN - m * m;
    float inv = rsqrtf(v + BEPS);
    float sc = g[c] * inv;
    scale[c] = sc;
    shift[c] = be[c] - m * sc;
}

// ---------------- BN fold into next conv (weights + bias, one kernel) -------
__global__ __launch_bounds__(256) void fold_wb(
    const float* __restrict__ w, const float* __restrict__ scale,
    const float* __restrict__ shift, const float* __restrict__ bias,
    ushort_t* __restrict__ wout, float* __restrict__ effb, int Ci, int Co) {
    if (blockIdx.y == 0) {
        int idx = blockIdx.x * 256 + threadIdx.x;
        int total = Co * Ci * 9;
        if (idx < total) {
            int ci = (idx / 9) % Ci;
            __hip_bfloat16 h = __float2bfloat16(w[idx] * scale[ci]);
            wout[idx] = *(ushort_t*)&h;
        }
    } else {
        int co = blockIdx.x * 256 + threadIdx.x;
        if (co < Co) {
            float acc = bias[co];
            const float* wr = w + (long long)co * Ci * 9;
            for (int ci = 0; ci < Ci; ++ci) {
                float sh = shift[ci];
#pragma unroll
                for (int t = 0; t < 9; ++t) acc = fmaf(wr[ci * 9 + t], sh, acc);
            }
            effb[co] = acc;
        }
    }
}

// ---------------- BN apply conv5 out (bf16) -> xT fp32 [k][32] --------------
__global__ void bn_apply_t(const __hip_bfloat16* __restrict__ y, const float* __restrict__ scale,
                           const float* __restrict__ shift, float* __restrict__ xT) {
    int idx = blockIdx.x * blockDim.x + threadIdx.x;
    if (idx >= 802816) return;
    int k = idx >> 5, b = idx & 31;
    int c = k / 49;
    xT[idx] = fmaf(__bfloat162float(y[(long long)b * 25088 + k]), scale[c], shift[c]);
}

// ---------------- fc1 split-K GEMM ------------------------------------------
__global__ __launch_bounds__(256) void fc1_gemm(const float* __restrict__ xT,
                                                const float* __restrict__ w,
                                                float* __restrict__ part) {
    const int K = 25088;
    __shared__ __align__(16) float As[16][64];
    __shared__ __align__(16) float Bs[16][32];
    const int tid = threadIdx.x;
    const int m0 = blockIdx.y * 64;
    const int kbeg = blockIdx.x * FC1_KC;
    const int cA = tid >> 2;
    const int kqA = (tid & 3) * 4;
    const int kkB = tid >> 5;
    const int bB = tid & 31;
    const int tm = tid >> 4;
    const int tn = tid & 15;

    const int mrow = m0 + cA;
    const bool mvalid = (mrow < 1000);
    const float* wrow = w + (long long)mrow * K + kbeg + kqA;

    float acc[4][2] = {};
    for (int k0 = 0; k0 < FC1_KC; k0 += 16) {
        float4 av = mvalid ? *(const float4*)(wrow + k0)
                           : make_float4(0.f, 0.f, 0.f, 0.f);
        As[kqA + 0][cA] = av.x;
        As[kqA + 1][cA] = av.y;
        As[kqA + 2][cA] = av.z;
        As[kqA + 3][cA] = av.w;
#pragma unroll
        for (int e = 0; e < 2; ++e) {
            int kk = kkB + e * 8;
            Bs[kk][bB] = xT[(kbeg + k0 + kk) * 32 + bB];
        }
        __syncthreads();
#pragma unroll
        for (int kk = 0; kk < 16; ++kk) {
            float4 a = *(const float4*)&As[kk][tm * 4];
            float b0 = Bs[kk][tn * 2 + 0];
            float b1 = Bs[kk][tn * 2 + 1];
            float a4[4] = {a.x, a.y, a.z, a.w};
#pragma unroll
            for (int mi = 0; mi < 4; ++mi) {
                acc[mi][0] = fmaf(a4[mi], b0, acc[mi][0]);
                acc[mi][1] = fmaf(a4[mi], b1, acc[mi][1]);
            }
        }
        __syncthreads();
    }
    float* pb = part + ((long long)blockIdx.y * FC1_KS + blockIdx.x) * 2048;
#pragma unroll
    for (int mi = 0; mi < 4; ++mi) {
        pb[(tm * 4 + mi) * 32 + tn * 2 + 0] = acc[mi][0];
        pb[(tm * 4 + mi) * 32 + tn * 2 + 1] = acc[mi][1];
    }
}

__global__ void fc1_reduce(const float* __restrict__ part, const float* __restrict__ bias,
                           float* __restrict__ z) {
    int idx = blockIdx.x * blockDim.x + threadIdx.x;
    if (idx >= 32000) return;
    int o = idx >> 5, b = idx & 31;
    int mt = o >> 6, mr = o & 63;
    const float* p = part + ((long long)mt * FC1_KS) * 2048 + mr * 32 + b;
    float s0 = 0.f, s1 = 0.f;
    int ks = 0;
    for (; ks + 1 < FC1_KS; ks += 2) {
        s0 += p[(long long)ks * 2048];
        s1 += p[(long long)(ks + 1) * 2048];
    }
    for (; ks < FC1_KS; ++ks) s0 += p[(long long)ks * 2048];
    z[b * 1000 + o] = fmaxf(s0 + s1 + bias[o], 0.f);
}

// ---------------- fc2 -------------------------------------------------------
__global__ __launch_bounds__(256) void fc2_v2(const float* __restrict__ z,
                                              const float* __restrict__ w,
                                              const float* __restrict__ bias,
                                              float* __restrict__ ys) {
    int gid = blockIdx.x * 4 + (threadIdx.x >> 6);
    int lane = threadIdx.x & 63;
    if (gid >= 960) return;
    int b = gid / 30, o = gid - b * 30;
    const float* zr = z + (long long)b * 1000;
    const float* wr = w + (long long)o * 1000;
    float acc = 0.f;
    for (int k = lane; k < 1000; k += 64) acc = fmaf(zr[k], wr[k], acc);
    for (int off = 32; off > 0; off >>= 1) acc += __shfl_down(acc, off, 64);
    if (lane == 0) ys[gid] = acc + bias[o];
}

// ---------------- spline coefficients -> float4 per segment -----------------
__global__ void spline_coeff(const float* __restrict__ ysraw, const float* __restrict__ matrix,
                             float4* __restrict__ coef) {
    int r = threadIdx.x;
    if (r >= 96) return;
    const float h = 1.0f / 9.0f;
    float ya[10];
    int b = r / 3, ch = r % 3;
#pragma unroll
    for (int j = 0; j < 10; ++j)
        ya[j] = ysraw[b * 30 + ch * 10 + j] / 100.0f + (float)j / 9.0f;
    float M[10];
#pragma unroll
    for (int i = 0; i < 10; ++i) {
        float acc = 0.f;
#pragma unroll
        for (int j = 0; j < 10; ++j) acc = fmaf(matrix[i * 10 + j], ya[j], acc);
        M[i] = acc;
    }
#pragma unroll
    for (int k = 0; k < 9; ++k) {
        float a = (M[k + 1] - M[k]) / (6.0f * h);
        float bb = M[k] * 0.5f;
        float cc = (ya[k + 1] - ya[k]) / h - (M[k + 1] + 2.0f * M[k]) * (h / 6.0f);
        float dd = ya[k];
        coef[r * 9 + k] = make_float4(a, bb, cc, dd);
    }
}

// ---------------- spline eval on the image (float4) -------------------------
__global__ void eval_img4(const float4* __restrict__ batch4, const float4* __restrict__ coef,
                          float4* __restrict__ out4) {
    int idx = blockIdx.x * blockDim.x + threadIdx.x;
    if (idx >= 1572864) return;
    int plane = idx >> 14;
    float4 xv4 = batch4[idx];
    const float h = 1.0f / 9.0f;
    float xin[4] = {xv4.x, xv4.y, xv4.z, xv4.w};
    float xout[4];
#pragma unroll
    for (int e = 0; e < 4; ++e) {
        float xv = xin[e];
        int xi = (int)floorf(xv / h);
        xi = min(max(xi, 0), 8);
        float xf = xv - (float)xi * h;
        float4 cf = coef[plane * 9 + xi];
        xout[e] = fmaf(fmaf(fmaf(cf.x, xf, cf.y), xf, cf.z), xf, cf.w);
    }
    out4[idx] = make_float4(xout[0], xout[1], xout[2], xout[3]);
}

// ---------------- spline eval on the 255-value table ------------------------
__global__ void eval_tab(const float4* __restrict__ coef, float* __restrict__ out, int total) {
    int idx = blockIdx.x * blockDim.x + threadIdx.x;
    if (idx >= total) return;
    int plane = idx / 255;
    int j = idx % 255;
    float xv = (float)j / 255.0f;
    const float h = 1.0f / 9.0f;
    int xi = (int)floorf(xv / h);
    xi = min(max(xi, 0), 8);
    float xf = xv - (float)xi * h;
    float4 cf = coef[plane * 9 + xi];
    out[idx] = fmaf(fmaf(fmaf(cf.x, xf, cf.y), xf, cf.z), xf, cf.w);
}

extern "C" void kernel_launch(void* const* d_in, const int* in_sizes, int n_in,
                              void* d_out, int out_size, void* d_ws, size_t ws_size,
                              hipStream_t stream) {
    const int B = 32;
    const float* batch = (const float*)d_in[0];
    const float* cw[5] = {(const float*)d_in[1], (const float*)d_in[5], (const float*)d_in[9],
                          (const float*)d_in[13], (const float*)d_in[17]};
    const float* cb[5] = {(const float*)d_in[2], (const float*)d_in[6], (const float*)d_in[10],
                          (const float*)d_in[14], (const float*)d_in[18]};
    const float* bg[5] = {(const float*)d_in[3], (const float*)d_in[7], (const float*)d_in[11],
                          (const float*)d_in[15], (const float*)d_in[19]};
    const float* bb[5] = {(const float*)d_in[4], (const float*)d_in[8], (const float*)d_in[12],
                          (const float*)d_in[16], (const float*)d_in[20]};
    const float* l1w = (const float*)d_in[21];
    const float* l1b = (const float*)d_in[22];
    const float* l2w = (const float*)d_in[23];
    const float* l2b = (const float*)d_in[24];
    const float* matrix = (const float*)d_in[25];

    float* f = (float*)d_ws;
    const size_t A_F = 8258048;
    const size_t Bq_F = 4064256;
    const size_t W_F = 589824;
    __hip_bfloat16* bufA_bf = (__hip_bfloat16*)f;
    __hip_bfloat16* bufB_bf = (__hip_bfloat16*)(f + A_F);
    ushort_t* Wf_bf = (ushort_t*)(f + A_F + Bq_F);
    float* effb  = f + A_F + Bq_F + W_F;   // 512
    float* scale = effb + 512;             // 512
    float* shift = scale + 512;            // 512
    float* part  = shift + 512;            // 8192
    float* x5    = part + 8192;            // 802,816
    float* fc1p  = x5 + 802816;            // 3,211,264 (shared with conv5 pacc)
    float* z1    = fc1p + 3211264;         // 32,000
    float* ysb   = z1 + 32000;             // 960
    float4* coef = (float4*)(ysb + 960);   // 96*9 float4

    const int Ci[5] = {3, 32, 64, 128, 256};
    const int Co[5] = {32, 64, 128, 256, 512};
    const int Hi[5] = {256, 127, 63, 31, 15};
    const int Ho[5] = {127, 63, 31, 15, 7};
    const int S = 8;

    __hip_bfloat16* bufs[2] = {bufA_bf, bufB_bf};

    // layer 1: direct conv, then vectorized stats
    conv1_direct<<<C1NB, 256, 0, stream>>>(batch, cw[0], cb[0], bufA_bf);
    stats_partial_v<<<dim3(32, S), 256, 0, stream>>>((const ushort_t*)bufA_bf, part,
                                                     B, 32, 16129, S);
    stats_final<<<1, 64, 0, stream>>>(part, bg[0], bb[0], scale, shift, 32, S,
                                      1.0f / (32.0f * 16129.0f));

    // layers 2..5: MFMA bf16
    const __hip_bfloat16* cur = bufA_bf;
    for (int l = 1; l < 5; ++l) {
        __hip_bfloat16* outb = bufs[l % 2];
        int K = Ci[l] * 9;
        int wtotal = Co[l] * K;
        dim3 fgrid((wtotal + 255) / 256, 2);
        fold_wb<<<fgrid, 256, 0, stream>>>(cw[l], scale, shift, cb[l], Wf_bf, effb,
                                           Ci[l], Co[l]);
        int N = B * Ho[l] * Ho[l];
        if (l < 4) {
            dim3 grid((N + 63) / 64, Co[l] / 64, 1);
            conv_mfma<<<grid, 256, 0, stream>>>(cur, Wf_bf, effb, outb, nullptr, B, Ci[l],
                                                Hi[l], Hi[l], Co[l], Ho[l], Ho[l], K, K);
        } else {
            dim3 grid((N + 63) / 64, Co[l] / 64, 3);
            conv_mfma<<<grid, 256, 0, stream>>>(cur, Wf_bf, effb, nullptr, fc1p, B, Ci[l],
                                                Hi[l], Hi[l], Co[l], Ho[l], Ho[l], K, 768);
            conv5_reduce<<<(512 * 1568 + 255) / 256, 256, 0, stream>>>(fc1p, effb, outb);
        }
        stats_partial_v<<<dim3(Co[l], S), 256, 0, stream>>>((const ushort_t*)outb, part,
                                                            B, Co[l], Ho[l] * Ho[l], S);
        stats_final<<<(Co[l] + 63) / 64, 64, 0, stream>>>(part, bg[l], bb[l], scale, shift,
                                                          Co[l], S, 1.0f / (B * Ho[l] * Ho[l]));
        cur = outb;
    }

    bn_apply_t<<<(802816 + 255) / 256, 256, 0, stream>>>(cur, scale, shift, x5);
    {
        dim3 grid(FC1_KS, 16);
        fc1_gemm<<<grid, 256, 0, stream>>>(x5, l1w, fc1p);
    }
    fc1_reduce<<<(32000 + 255) / 256, 256, 0, stream>>>(fc1p, l1b, z1);
    fc2_v2<<<240, 256, 0, stream>>>(z1, l2w, l2b, ysb);
    spline_coeff<<<1, 96, 0, stream>>>(ysb, matrix, coef);

    float* out = (float*)d_out;
    eval_img4<<<(1572864 + 255) / 256, 256, 0, stream>>>((const float4*)batch, coef,
                                                         (float4*)out);
    eval_tab<<<(96 * 255 + 255) / 256, 256, 0, stream>>>(coef, out + 6291456, 96 * 255);
}

// Round 8
// 448.737 us; speedup vs baseline: 1.3579x; 1.3579x over previous
//
#include <hip/hip_runtime.h>
#include <hip/hip_bf16.h>

#define BEPS 1e-5f
#define FC1_KS 98
#define FC1_KC 256
#define C1NB 2017

typedef __attribute__((ext_vector_type(8))) short short8v;
typedef __attribute__((ext_vector_type(4))) float f32x4;
typedef unsigned short ushort_t;

__device__ __forceinline__ float bf2f(ushort_t u) {
    unsigned int x = ((unsigned int)u) << 16;
    return __builtin_bit_cast(float, x);
}

// ---------------- conv1: direct fp32, bf16 out (no stats) -------------------
__global__ __launch_bounds__(256) void conv1_direct(
    const float* __restrict__ in, const float* __restrict__ w,
    const float* __restrict__ bias, __hip_bfloat16* __restrict__ out) {
    __shared__ float ws[864];
    __shared__ float bs[32];
    const int tid = threadIdx.x;
    for (int i = tid; i < 864; i += 256) ws[i] = w[i];
    if (tid < 32) bs[tid] = bias[tid];
    __syncthreads();

    const int TOT = 32 * 16129;
    int p = blockIdx.x * 256 + tid;
    if (p >= TOT) return;
    int b = p / 16129, pp = p - b * 16129;
    int i = pp / 127, j = pp - i * 127;
    const float* ib = in + ((long long)b * 3) * 65536 + (2 * i) * 256 + 2 * j;
    float patch[27];
#pragma unroll
    for (int ci = 0; ci < 3; ++ci)
#pragma unroll
        for (int di = 0; di < 3; ++di) {
            const float* rp = ib + ci * 65536 + di * 256;
            float2 v01 = *(const float2*)rp;
            patch[ci * 9 + di * 3 + 0] = v01.x;
            patch[ci * 9 + di * 3 + 1] = v01.y;
            patch[ci * 9 + di * 3 + 2] = rp[2];
        }

#pragma unroll
    for (int co = 0; co < 32; co += 4) {
        float a0 = bs[co], a1 = bs[co + 1], a2 = bs[co + 2], a3 = bs[co + 3];
#pragma unroll
        for (int t = 0; t < 27; ++t) {
            float pv = patch[t];
            a0 = fmaf(pv, ws[(co + 0) * 27 + t], a0);
            a1 = fmaf(pv, ws[(co + 1) * 27 + t], a1);
            a2 = fmaf(pv, ws[(co + 2) * 27 + t], a2);
            a3 = fmaf(pv, ws[(co + 3) * 27 + t], a3);
        }
        out[((long long)b * 32 + co + 0) * 16129 + pp] = __float2bfloat16(fmaxf(a0, 0.f));
        out[((long long)b * 32 + co + 1) * 16129 + pp] = __float2bfloat16(fmaxf(a1, 0.f));
        out[((long long)b * 32 + co + 2) * 16129 + pp] = __float2bfloat16(fmaxf(a2, 0.f));
        out[((long long)b * 32 + co + 3) * 16129 + pp] = __float2bfloat16(fmaxf(a3, 0.f));
    }
}

// ---------------- convs 2-5: bf16 MFMA implicit GEMM ------------------------
__global__ __launch_bounds__(256) void conv_mfma(
    const __hip_bfloat16* __restrict__ in, const ushort_t* __restrict__ wf,
    const float* __restrict__ effb, __hip_bfloat16* __restrict__ out,
    float* __restrict__ pacc,
    int B, int Ci, int Hi, int Wi, int Co, int Ho, int Wo, int K, int kcount) {
    const int HoWo = Ho * Wo;
    const int N = B * HoWo;
    const int HiWi = Hi * Wi;
    __shared__ __align__(16) ushort_t As[64 * 40];
    __shared__ __align__(16) ushort_t Bs[64 * 40];
    __shared__ int koff[1152];
    const int tid = threadIdx.x;
    const int m0 = blockIdx.y * 64;
    const int n0 = blockIdx.x * 64;
    const int kbeg = blockIdx.z * kcount;

    for (int k = tid; k < kcount; k += 256) {
        int kg = kbeg + k;
        int ci = kg / 9, r = kg - ci * 9;
        int dy = r / 3, dx = r - dy * 3;
        koff[k] = ci * HiWi + dy * Wi + dx;
    }

    const int srow = tid >> 2;
    const int skq = (tid & 3) * 8;
    const int n = n0 + srow;
    const bool nv = (n < N);
    const int nn = nv ? n : 0;
    const int pb = nn / HoWo, pp = nn - pb * HoWo;
    const int pi = pp / Wo, pj = pp - pi * Wo;
    const long long binbase = (long long)pb * Ci * HiWi + (2 * pi) * Wi + 2 * pj;
    const ushort_t* inq = (const ushort_t*)in;
    const ushort_t* wrow = wf + (long long)(m0 + srow) * K + kbeg + skq;

    const int wid = tid >> 6;
    const int lane = tid & 63;
    const int wr = wid >> 1, wc = wid & 1;
    const int lm = lane & 15, lk = lane >> 4;

    __syncthreads();  // koff ready

    f32x4 acc[2][2] = {};
    for (int k0 = 0; k0 < kcount; k0 += 32) {
        *(short8v*)&As[srow * 40 + skq] = *(const short8v*)(wrow + k0);
        short8v bvv;
#pragma unroll
        for (int j = 0; j < 8; ++j) {
            ushort_t v = nv ? inq[binbase + koff[k0 + skq + j]] : (ushort_t)0;
            bvv[j] = (short)v;
        }
        *(short8v*)&Bs[srow * 40 + skq] = bvv;
        __syncthreads();
        short8v a0 = *(const short8v*)&As[(wr * 32 + lm) * 40 + lk * 8];
        short8v a1 = *(const short8v*)&As[(wr * 32 + 16 + lm) * 40 + lk * 8];
        short8v b0 = *(const short8v*)&Bs[(wc * 32 + lm) * 40 + lk * 8];
        short8v b1 = *(const short8v*)&Bs[(wc * 32 + 16 + lm) * 40 + lk * 8];
        acc[0][0] = __builtin_amdgcn_mfma_f32_16x16x32_bf16(a0, b0, acc[0][0], 0, 0, 0);
        acc[0][1] = __builtin_amdgcn_mfma_f32_16x16x32_bf16(a0, b1, acc[0][1], 0, 0, 0);
        acc[1][0] = __builtin_amdgcn_mfma_f32_16x16x32_bf16(a1, b0, acc[1][0], 0, 0, 0);
        acc[1][1] = __builtin_amdgcn_mfma_f32_16x16x32_bf16(a1, b1, acc[1][1], 0, 0, 0);
        __syncthreads();
    }
    if (pacc) {
        float* pbuf = pacc + (long long)blockIdx.z * Co * N;
#pragma unroll
        for (int nc = 0; nc < 2; ++nc) {
            int np = n0 + wc * 32 + nc * 16 + lm;
            if (np >= N) continue;
#pragma unroll
            for (int mr = 0; mr < 2; ++mr) {
                int cobase = m0 + wr * 32 + mr * 16 + lk * 4;
#pragma unroll
                for (int r = 0; r < 4; ++r)
                    pbuf[(long long)(cobase + r) * N + np] = acc[mr][nc][r];
            }
        }
    } else {
#pragma unroll
        for (int nc = 0; nc < 2; ++nc) {
            int np = n0 + wc * 32 + nc * 16 + lm;
            if (np >= N) continue;
            int ob = np / HoWo, op = np - ob * HoWo;
#pragma unroll
            for (int mr = 0; mr < 2; ++mr) {
                int cobase = m0 + wr * 32 + mr * 16 + lk * 4;
#pragma unroll
                for (int r = 0; r < 4; ++r) {
                    int co = cobase + r;
                    float v = fmaxf(acc[mr][nc][r] + effb[co], 0.f);
                    out[((long long)ob * Co + co) * HoWo + op] = __float2bfloat16(v);
                }
            }
        }
    }
}

// reduce conv5 K-split partials + bias + relu -> bf16 NCHW
__global__ void conv5_reduce(const float* __restrict__ pacc, const float* __restrict__ effb,
                             __hip_bfloat16* __restrict__ out) {
    int idx = blockIdx.x * 256 + threadIdx.x;
    if (idx >= 512 * 1568) return;
    int co = idx / 1568, n = idx - co * 1568;
    const long long st = (long long)512 * 1568;
    float s = pacc[(long long)co * 1568 + n] + pacc[st + (long long)co * 1568 + n] +
              pacc[2 * st + (long long)co * 1568 + n] + effb[co];
    s = fmaxf(s, 0.f);
    int b = n / 49, p = n - b * 49;
    out[((long long)b * 512 + co) * 49 + p] = __float2bfloat16(s);
}

// ---------------- BN stats (bf16 input), vectorized short8 ------------------
__global__ __launch_bounds__(256) void stats_partial_v(
    const ushort_t* __restrict__ y, float* __restrict__ part,
    int B, int C, int HW, int S) {
    const int c = blockIdx.x;
    const int s = blockIdx.y;
    const int tid = threadIdx.x;
    float sum = 0.f, sq = 0.f;
    for (int b = 0; b < B; ++b) {
        long long base = ((long long)b * C + c) * HW;
        long long end = base + HW;
        long long a0 = (base + 7) & ~7LL;
        long long a1 = end & ~7LL;
        if (s == 0) {
            int hn = (int)(a0 - base);
            if (tid < hn) {
                float v = bf2f(y[base + tid]);
                sum += v; sq = fmaf(v, v, sq);
            }
            int tn = (int)(end - a1);
            if (tid >= 8 && tid < 8 + tn) {
                float v = bf2f(y[a1 + tid - 8]);
                sum += v; sq = fmaf(v, v, sq);
            }
        }
        int nv8 = (int)((a1 - a0) >> 3);
        for (int ch = s * 256 + tid; ch < nv8; ch += S * 256) {
            short8v v8 = *(const short8v*)(y + a0 + (long long)ch * 8);
#pragma unroll
            for (int j = 0; j < 8; ++j) {
                float v = bf2f((ushort_t)v8[j]);
                sum += v; sq = fmaf(v, v, sq);
            }
        }
    }
    __shared__ float ls[256], lq[256];
    ls[tid] = sum; lq[tid] = sq;
    __syncthreads();
    for (int o = 128; o > 0; o >>= 1) {
        if (tid < o) { ls[tid] += ls[tid + o]; lq[tid] += lq[tid + o]; }
        __syncthreads();
    }
    if (tid == 0) {
        part[(c * S + s) * 2 + 0] = ls[0];
        part[(c * S + s) * 2 + 1] = lq[0];
    }
}

__global__ void stats_final(const float* __restrict__ part, const float* __restrict__ g,
                            const float* __restrict__ be, float* __restrict__ scale,
                            float* __restrict__ shift, int C, int S, float invN) {
    int c = blockIdx.x * blockDim.x + threadIdx.x;
    if (c >= C) return;
    float s = 0.f, q = 0.f;
    for (int i = 0; i < S; ++i) {
        s += part[(c * S + i) * 2 + 0];
        q += part[(c * S + i) * 2 + 1];
    }
    float m = s * invN;
    float v = q * invN - m * m;
    float inv = rsqrtf(v + BEPS);
    float sc = g[c] * inv;
    scale[c] = sc;
    shift[c] = be[c] - m * sc;
}

// ---------------- BN fold: weights (parallel elementwise) -------------------
__global__ void fold_w_bf(const float* __restrict__ w, const float* __restrict__ scale,
                          ushort_t* __restrict__ wout, int Ci, int total) {
    int idx = blockIdx.x * blockDim.x + threadIdx.x;
    if (idx >= total) return;
    int ci = (idx / 9) % Ci;
    __hip_bfloat16 h = __float2bfloat16(w[idx] * scale[ci]);
    wout[idx] = *(ushort_t*)&h;
}

// ---------------- BN fold: bias via wave-per-co coalesced reduction ---------
__global__ __launch_bounds__(256) void fold_b_v2(
    const float* __restrict__ w, const float* __restrict__ shift,
    const float* __restrict__ bias, float* __restrict__ effb, int Co, int Ci) {
    const int co = blockIdx.x * 4 + (threadIdx.x >> 6);
    const int lane = threadIdx.x & 63;
    if (co >= Co) return;
    const int CK = Ci * 9;
    const float* wr = w + (long long)co * CK;
    float acc = 0.f;
    for (int k = lane; k < CK; k += 64) acc = fmaf(wr[k], shift[k / 9], acc);
#pragma unroll
    for (int off = 32; off > 0; off >>= 1) acc += __shfl_down(acc, off, 64);
    if (lane == 0) effb[co] = acc + bias[co];
}

// ---------------- BN apply conv5 out (bf16) -> xT fp32 [k][32] --------------
__global__ void bn_apply_t(const __hip_bfloat16* __restrict__ y, const float* __restrict__ scale,
                           const float* __restrict__ shift, float* __restrict__ xT) {
    int idx = blockIdx.x * blockDim.x + threadIdx.x;
    if (idx >= 802816) return;
    int k = idx >> 5, b = idx & 31;
    int c = k / 49;
    xT[idx] = fmaf(__bfloat162float(y[(long long)b * 25088 + k]), scale[c], shift[c]);
}

// ---------------- fc1 split-K GEMM ------------------------------------------
__global__ __launch_bounds__(256) void fc1_gemm(const float* __restrict__ xT,
                                                const float* __restrict__ w,
                                                float* __restrict__ part) {
    const int K = 25088;
    __shared__ __align__(16) float As[16][64];
    __shared__ __align__(16) float Bs[16][32];
    const int tid = threadIdx.x;
    const int m0 = blockIdx.y * 64;
    const int kbeg = blockIdx.x * FC1_KC;
    const int cA = tid >> 2;
    const int kqA = (tid & 3) * 4;
    const int kkB = tid >> 5;
    const int bB = tid & 31;
    const int tm = tid >> 4;
    const int tn = tid & 15;

    const int mrow = m0 + cA;
    const bool mvalid = (mrow < 1000);
    const float* wrow = w + (long long)mrow * K + kbeg + kqA;

    float acc[4][2] = {};
    for (int k0 = 0; k0 < FC1_KC; k0 += 16) {
        float4 av = mvalid ? *(const float4*)(wrow + k0)
                           : make_float4(0.f, 0.f, 0.f, 0.f);
        As[kqA + 0][cA] = av.x;
        As[kqA + 1][cA] = av.y;
        As[kqA + 2][cA] = av.z;
        As[kqA + 3][cA] = av.w;
#pragma unroll
        for (int e = 0; e < 2; ++e) {
            int kk = kkB + e * 8;
            Bs[kk][bB] = xT[(kbeg + k0 + kk) * 32 + bB];
        }
        __syncthreads();
#pragma unroll
        for (int kk = 0; kk < 16; ++kk) {
            float4 a = *(const float4*)&As[kk][tm * 4];
            float b0 = Bs[kk][tn * 2 + 0];
            float b1 = Bs[kk][tn * 2 + 1];
            float a4[4] = {a.x, a.y, a.z, a.w};
#pragma unroll
            for (int mi = 0; mi < 4; ++mi) {
                acc[mi][0] = fmaf(a4[mi], b0, acc[mi][0]);
                acc[mi][1] = fmaf(a4[mi], b1, acc[mi][1]);
            }
        }
        __syncthreads();
    }
    float* pb = part + ((long long)blockIdx.y * FC1_KS + blockIdx.x) * 2048;
#pragma unroll
    for (int mi = 0; mi < 4; ++mi) {
        pb[(tm * 4 + mi) * 32 + tn * 2 + 0] = acc[mi][0];
        pb[(tm * 4 + mi) * 32 + tn * 2 + 1] = acc[mi][1];
    }
}

__global__ void fc1_reduce(const float* __restrict__ part, const float* __restrict__ bias,
                           float* __restrict__ z) {
    int idx = blockIdx.x * blockDim.x + threadIdx.x;
    if (idx >= 32000) return;
    int o = idx >> 5, b = idx & 31;
    int mt = o >> 6, mr = o & 63;
    const float* p = part + ((long long)mt * FC1_KS) * 2048 + mr * 32 + b;
    float s0 = 0.f, s1 = 0.f;
    int ks = 0;
    for (; ks + 1 < FC1_KS; ks += 2) {
        s0 += p[(long long)ks * 2048];
        s1 += p[(long long)(ks + 1) * 2048];
    }
    for (; ks < FC1_KS; ++ks) s0 += p[(long long)ks * 2048];
    z[b * 1000 + o] = fmaxf(s0 + s1 + bias[o], 0.f);
}

// ---------------- fc2 -------------------------------------------------------
__global__ __launch_bounds__(256) void fc2_v2(const float* __restrict__ z,
                                              const float* __restrict__ w,
                                              const float* __restrict__ bias,
                                              float* __restrict__ ys) {
    int gid = blockIdx.x * 4 + (threadIdx.x >> 6);
    int lane = threadIdx.x & 63;
    if (gid >= 960) return;
    int b = gid / 30, o = gid - b * 30;
    const float* zr = z + (long long)b * 1000;
    const float* wr = w + (long long)o * 1000;
    float acc = 0.f;
    for (int k = lane; k < 1000; k += 64) acc = fmaf(zr[k], wr[k], acc);
    for (int off = 32; off > 0; off >>= 1) acc += __shfl_down(acc, off, 64);
    if (lane == 0) ys[gid] = acc + bias[o];
}

// ---------------- spline coefficients -> float4 per segment -----------------
__global__ void spline_coeff(const float* __restrict__ ysraw, const float* __restrict__ matrix,
                             float4* __restrict__ coef) {
    int r = threadIdx.x;
    if (r >= 96) return;
    const float h = 1.0f / 9.0f;
    float ya[10];
    int b = r / 3, ch = r % 3;
#pragma unroll
    for (int j = 0; j < 10; ++j)
        ya[j] = ysraw[b * 30 + ch * 10 + j] / 100.0f + (float)j / 9.0f;
    float M[10];
#pragma unroll
    for (int i = 0; i < 10; ++i) {
        float acc = 0.f;
#pragma unroll
        for (int j = 0; j < 10; ++j) acc = fmaf(matrix[i * 10 + j], ya[j], acc);
        M[i] = acc;
    }
#pragma unroll
    for (int k = 0; k < 9; ++k) {
        float a = (M[k + 1] - M[k]) / (6.0f * h);
        float bb = M[k] * 0.5f;
        float cc = (ya[k + 1] - ya[k]) / h - (M[k + 1] + 2.0f * M[k]) * (h / 6.0f);
        float dd = ya[k];
        coef[r * 9 + k] = make_float4(a, bb, cc, dd);
    }
}

// ---------------- spline eval on the image (float4) -------------------------
__global__ void eval_img4(const float4* __restrict__ batch4, const float4* __restrict__ coef,
                          float4* __restrict__ out4) {
    int idx = blockIdx.x * blockDim.x + threadIdx.x;
    if (idx >= 1572864) return;
    int plane = idx >> 14;
    float4 xv4 = batch4[idx];
    const float h = 1.0f / 9.0f;
    float xin[4] = {xv4.x, xv4.y, xv4.z, xv4.w};
    float xout[4];
#pragma unroll
    for (int e = 0; e < 4; ++e) {
        float xv = xin[e];
        int xi = (int)floorf(xv / h);
        xi = min(max(xi, 0), 8);
        float xf = xv - (float)xi * h;
        float4 cf = coef[plane * 9 + xi];
        xout[e] = fmaf(fmaf(fmaf(cf.x, xf, cf.y), xf, cf.z), xf, cf.w);
    }
    out4[idx] = make_float4(xout[0], xout[1], xout[2], xout[3]);
}

// ---------------- spline eval on the 255-value table ------------------------
__global__ void eval_tab(const float4* __restrict__ coef, float* __restrict__ out, int total) {
    int idx = blockIdx.x * blockDim.x + threadIdx.x;
    if (idx >= total) return;
    int plane = idx / 255;
    int j = idx % 255;
    float xv = (float)j / 255.0f;
    const float h = 1.0f / 9.0f;
    int xi = (int)floorf(xv / h);
    xi = min(max(xi, 0), 8);
    float xf = xv - (float)xi * h;
    float4 cf = coef[plane * 9 + xi];
    out[idx] = fmaf(fmaf(fmaf(cf.x, xf, cf.y), xf, cf.z), xf, cf.w);
}

extern "C" void kernel_launch(void* const* d_in, const int* in_sizes, int n_in,
                              void* d_out, int out_size, void* d_ws, size_t ws_size,
                              hipStream_t stream) {
    const int B = 32;
    const float* batch = (const float*)d_in[0];
    const float* cw[5] = {(const float*)d_in[1], (const float*)d_in[5], (const float*)d_in[9],
                          (const float*)d_in[13], (const float*)d_in[17]};
    const float* cb[5] = {(const float*)d_in[2], (const float*)d_in[6], (const float*)d_in[10],
                          (const float*)d_in[14], (const float*)d_in[18]};
    const float* bg[5] = {(const float*)d_in[3], (const float*)d_in[7], (const float*)d_in[11],
                          (const float*)d_in[15], (const float*)d_in[19]};
    const float* bb[5] = {(const float*)d_in[4], (const float*)d_in[8], (const float*)d_in[12],
                          (const float*)d_in[16], (const float*)d_in[20]};
    const float* l1w = (const float*)d_in[21];
    const float* l1b = (const float*)d_in[22];
    const float* l2w = (const float*)d_in[23];
    const float* l2b = (const float*)d_in[24];
    const float* matrix = (const float*)d_in[25];

    float* f = (float*)d_ws;
    const size_t A_F = 8258048;
    const size_t Bq_F = 4064256;
    const size_t W_F = 589824;
    __hip_bfloat16* bufA_bf = (__hip_bfloat16*)f;
    __hip_bfloat16* bufB_bf = (__hip_bfloat16*)(f + A_F);
    ushort_t* Wf_bf = (ushort_t*)(f + A_F + Bq_F);
    float* effb  = f + A_F + Bq_F + W_F;   // 512
    float* scale = effb + 512;             // 512
    float* shift = scale + 512;            // 512
    float* part  = shift + 512;            // 8192
    float* x5    = part + 8192;            // 802,816
    float* fc1p  = x5 + 802816;            // 3,211,264 (shared with conv5 pacc)
    float* z1    = fc1p + 3211264;         // 32,000
    float* ysb   = z1 + 32000;             // 960
    float4* coef = (float4*)(ysb + 960);   // 96*9 float4

    const int Ci[5] = {3, 32, 64, 128, 256};
    const int Co[5] = {32, 64, 128, 256, 512};
    const int Hi[5] = {256, 127, 63, 31, 15};
    const int Ho[5] = {127, 63, 31, 15, 7};
    const int S = 8;

    __hip_bfloat16* bufs[2] = {bufA_bf, bufB_bf};

    // layer 1: direct conv, then vectorized stats
    conv1_direct<<<C1NB, 256, 0, stream>>>(batch, cw[0], cb[0], bufA_bf);
    stats_partial_v<<<dim3(32, S), 256, 0, stream>>>((const ushort_t*)bufA_bf, part,
                                                     B, 32, 16129, S);
    stats_final<<<1, 64, 0, stream>>>(part, bg[0], bb[0], scale, shift, 32, S,
                                      1.0f / (32.0f * 16129.0f));

    // layers 2..5: MFMA bf16
    const __hip_bfloat16* cur = bufA_bf;
    for (int l = 1; l < 5; ++l) {
        __hip_bfloat16* outb = bufs[l % 2];
        int K = Ci[l] * 9;
        int wtotal = Co[l] * K;
        fold_w_bf<<<(wtotal + 255) / 256, 256, 0, stream>>>(cw[l], scale, Wf_bf, Ci[l], wtotal);
        fold_b_v2<<<(Co[l] + 3) / 4, 256, 0, stream>>>(cw[l], shift, cb[l], effb, Co[l], Ci[l]);
        int N = B * Ho[l] * Ho[l];
        if (l < 4) {
            dim3 grid((N + 63) / 64, Co[l] / 64, 1);
            conv_mfma<<<grid, 256, 0, stream>>>(cur, Wf_bf, effb, outb, nullptr, B, Ci[l],
                                                Hi[l], Hi[l], Co[l], Ho[l], Ho[l], K, K);
        } else {
            dim3 grid((N + 63) / 64, Co[l] / 64, 3);
            conv_mfma<<<grid, 256, 0, stream>>>(cur, Wf_bf, effb, nullptr, fc1p, B, Ci[l],
                                                Hi[l], Hi[l], Co[l], Ho[l], Ho[l], K, 768);
            conv5_reduce<<<(512 * 1568 + 255) / 256, 256, 0, stream>>>(fc1p, effb, outb);
        }
        stats_partial_v<<<dim3(Co[l], S), 256, 0, stream>>>((const ushort_t*)outb, part,
                                                            B, Co[l], Ho[l] * Ho[l], S);
        stats_final<<<(Co[l] + 63) / 64, 64, 0, stream>>>(part, bg[l], bb[l], scale, shift,
                                                          Co[l], S, 1.0f / (B * Ho[l] * Ho[l]));
        cur = outb;
    }

    bn_apply_t<<<(802816 + 255) / 256, 256, 0, stream>>>(cur, scale, shift, x5);
    {
        dim3 grid(FC1_KS, 16);
        fc1_gemm<<<grid, 256, 0, stream>>>(x5, l1w, fc1p);
    }
    fc1_reduce<<<(32000 + 255) / 256, 256, 0, stream>>>(fc1p, l1b, z1);
    fc2_v2<<<240, 256, 0, stream>>>(z1, l2w, l2b, ysb);
    spline_coeff<<<1, 96, 0, stream>>>(ysb, matrix, coef);

    float* out = (float*)d_out;
    eval_img4<<<(1572864 + 255) / 256, 256, 0, stream>>>((const float4*)batch, coef,
                                                         (float4*)out);
    eval_tab<<<(96 * 255 + 255) / 256, 256, 0, stream>>>(coef, out + 6291456, 96 * 255);
}